// Round 18
// baseline (143.627 us; speedup 1.0000x reference)
//
#include <hip/hip_runtime.h>

typedef __bf16 bf16;
typedef __bf16 bf16x4 __attribute__((ext_vector_type(4)));
typedef __bf16 bf16x8 __attribute__((ext_vector_type(8)));
typedef float  f32x4  __attribute__((ext_vector_type(4)));

#define MFMA16(a, b, c) __builtin_amdgcn_mfma_f32_16x16x32_bf16((a), (b), (c), 0, 0, 0)

// R18 = R17 (65.2us best) with the BASE COMPUTED BY MFMA (rank-3 outer product):
//  * base[k][q] = x_k*W1[q] + ap_k*v3p[q] + bn_k*v3m[q] = one K=32 MFMA using
//    9 K-slots with hi/lo double-bf16 pairing (W1h*xh, W1l*xh, W1h*xl, ...):
//    error ~2^-16 << mu bf16 quantization. A-frags aB[qt] (W1/v3p/v3m hi+lo
//    per q-row) are MFMA A-operands -> AGPR-side (16 regs).
//  * W2 frags stored NEGATED (w2n): chain MFMA(aB,bB,0) -> MFMA(w2n,m0,.) ->
//    MFMA(w2n,m1,.) = base - acc; v = max(a + s2, 0). s2 extract negated.
//  * DELETES the 48-reg w1C/v3pC/v3mC block + 48 FMA/kt epilogue + prologue.
//    R17 autopsy: VGPR still pinned 128, 1.3MB residual scratch -- this was
//    the last big arch block. New arch-live ~60, AGPR ~65.
// LAUNCH-BOUNDS RULE (R2/R4/R8): never min-waves>2. SPILL TRIPWIRE: VGPR
// pinned 128 + FETCH>>2.5MB => revert to R17.
__global__ __launch_bounds__(64, 2)
void qnet_kernel(const float* __restrict__ Xg, const float* __restrict__ Wg,
                 const float* __restrict__ W1g, const float* __restrict__ W2g,
                 const float* __restrict__ W3g, const float* __restrict__ W4g,
                 const float* __restrict__ W5g, const float* __restrict__ W6g,
                 const float* __restrict__ W7g, float* __restrict__ Outg)
{
    __shared__ __align__(16) bf16 muS[128 * 64];   // 16384 B, packed + swizzled
    __shared__ __align__(16) float uS[64];         // 256 B
    __shared__ __align__(16) float smS[64];        // 256 B  sumMu broadcast

    const int lane = threadIdx.x;       // 0..63, one wave
    const int b    = blockIdx.x;
    const int l15  = lane & 15;
    const int quad = lane >> 4;
    const int sw   = l15 & 7;           // swizzle key: k&7 == l15&7 for k=16kt+l15

    // ---------------- per-batch vectors (6 persistent arch regs) ----------------
    float xv0 = Xg[b * 128 + lane], xv1 = Xg[b * 128 + 64 + lane];
    float wv0 = Wg[b * 128 + lane], wv1 = Wg[b * 128 + 64 + lane];

    float Ap = fmaxf(wv0, 0.f) + fmaxf(wv1, 0.f);
    float Bn = fmaxf(-wv0, 0.f) + fmaxf(-wv1, 0.f);
#pragma unroll
    for (int m = 1; m < 64; m <<= 1) { Ap += __shfl_xor(Ap, m); Bn += __shfl_xor(Bn, m); }

    // v3p/v3m at q=lane (exact fp32)
    float sp = 0.f, sm = 0.f;
#pragma unroll
    for (int c = 0; c < 16; ++c) {
        f32x4 w4 = *(const f32x4*)&W4g[c * 4];
        f32x4 w3 = *(const f32x4*)&W3g[lane * 64 + c * 4];
#pragma unroll
        for (int e = 0; e < 4; ++e) {
            sp += fmaxf(w4[e], 0.f) * w3[e];
            sm += fmaxf(-w4[e], 0.f) * w3[e];
        }
    }

    // base-MFMA A-frags: aB[qt], row q = qt*16 + l15, K-slots (quad0 j0..7, quad1 j0):
    //  {W1h, W1l, W1h, v3ph, v3pl, v3ph, v3mh, v3ml} , quad1 j0 = v3mh  (pairs with B below)
    bf16x8 aB[4];
    {
        float w1l_ = W1g[lane];
#pragma unroll
        for (int qt = 0; qt < 4; ++qt) {
            const int q = qt * 16 + l15;
            float w1q = __shfl(w1l_, q);
            float spq = __shfl(sp, q);
            float smq = __shfl(sm, q);
            bf16 w1h = (bf16)w1q; bf16 w1lo = (bf16)(w1q - (float)w1h);
            bf16 vph = (bf16)spq; bf16 vplo = (bf16)(spq - (float)vph);
            bf16 vmh = (bf16)smq; bf16 vmlo = (bf16)(smq - (float)vmh);
            bf16x8 a;
            const bf16 z = (bf16)0.f;
            a[0] = (quad == 0) ? w1h  : ((quad == 1) ? vmh : z);
            a[1] = (quad == 0) ? w1lo : z;
            a[2] = (quad == 0) ? w1h  : z;
            a[3] = (quad == 0) ? vph  : z;
            a[4] = (quad == 0) ? vplo : z;
            a[5] = (quad == 0) ? vph  : z;
            a[6] = (quad == 0) ? vmh  : z;
            a[7] = (quad == 0) ? vmlo : z;
            aB[qt] = a;
        }
    }

    // u[p=lane] = W5b @ W7[:,p] -> uS (wave-private LDS)
    {
        float u = 0.f;
#pragma unroll
        for (int c = 0; c < 16; ++c) {
            f32x4 w5v = *(const f32x4*)&W5g[64 + c * 4];
#pragma unroll
            for (int e = 0; e < 4; ++e) u += w5v[e] * W7g[(c * 4 + e) * 64 + lane];
        }
        uS[lane] = u;
    }

    // NEGATED W2 A-fragments (bf16 hi only): chain gives base - acc directly
    bf16x8 w2n[4][2];
#pragma unroll
    for (int qt = 0; qt < 4; ++qt)
#pragma unroll
        for (int s = 0; s < 2; ++s) {
            const float* src = &W2g[(qt * 16 + l15) * 64 + s * 32 + quad * 8];
            f32x4 f0 = *(const f32x4*)src;
            f32x4 f1 = *(const f32x4*)(src + 4);
            bf16x8 h;
#pragma unroll
            for (int e = 0; e < 4; ++e) { h[e] = (bf16)(-f0[e]); h[4 + e] = (bf16)(-f1[e]); }
            w2n[qt][s] = h;
        }

    // helper lambda-ish macro: build per-kt B-frag for the base MFMA
    //  quad0: {xh, xh, xl, ah, ah, al, bh, bh}; quad1: {bl,0,...}; else 0
#define BUILD_BB(bB_, kt_)                                                      \
    {                                                                           \
        const int src_ = ((kt_) & 3) * 16 + l15;                                \
        float xs_ = __shfl(((kt_) < 4) ? xv0 : xv1, src_);                      \
        float ws_ = __shfl(((kt_) < 4) ? wv0 : wv1, src_);                      \
        float ap_ = Ap - fmaxf(ws_, 0.f);                                       \
        float bn_ = Bn - fmaxf(-ws_, 0.f);                                      \
        bf16 xh = (bf16)xs_; bf16 xl = (bf16)(xs_ - (float)xh);                 \
        bf16 ah = (bf16)ap_; bf16 al = (bf16)(ap_ - (float)ah);                 \
        bf16 bh = (bf16)bn_; bf16 bl = (bf16)(bn_ - (float)bh);                 \
        const bf16 z_ = (bf16)0.f;                                              \
        bB_[0] = (quad == 0) ? xh : ((quad == 1) ? bl : z_);                    \
        bB_[1] = (quad == 0) ? xh : z_;                                         \
        bB_[2] = (quad == 0) ? xl : z_;                                         \
        bB_[3] = (quad == 0) ? ah : z_;                                         \
        bB_[4] = (quad == 0) ? ah : z_;                                         \
        bB_[5] = (quad == 0) ? al : z_;                                         \
        bB_[6] = (quad == 0) ? bh : z_;                                         \
        bB_[7] = (quad == 0) ? bh : z_;                                         \
    }

    const f32x4 zero4 = {0.f, 0.f, 0.f, 0.f};

    // ---------------- mu1 = relu(base-by-MFMA); accumulate smv ----------------
    float smv[16];
#pragma unroll
    for (int i = 0; i < 16; ++i) smv[i] = 0.f;
#pragma unroll
    for (int kt = 0; kt < 8; ++kt) {
        bf16x8 bB; BUILD_BB(bB, kt);
        const int row = (kt * 16 + l15) * 64;
#pragma unroll
        for (int qt = 0; qt < 4; ++qt) {
            f32x4 a = MFMA16(aB[qt], bB, zero4);
            bf16x4 h;
#pragma unroll
            for (int e = 0; e < 4; ++e) {
                float v = fmaxf(a[e], 0.f);
                smv[qt * 4 + e] += v;
                h[e] = (bf16)v;
            }
            *(bf16x4*)&muS[row + ((2 * qt + (quad >> 1)) ^ sw) * 8 + 4 * (quad & 1)] = h;
        }
    }

    // ---------------- 3 iterations, zero barriers ----------------
    for (int it = 0; it < 3; ++it) {
        // sumMu: l15 butterfly + publish to smS
#pragma unroll
        for (int m = 1; m <= 8; m <<= 1)
#pragma unroll
            for (int i = 0; i < 16; ++i) smv[i] += __shfl_xor(smv[i], m);
        if (l15 == 0) {
#pragma unroll
            for (int qt = 0; qt < 4; ++qt) {
                f32x4 v = {smv[qt * 4], smv[qt * 4 + 1], smv[qt * 4 + 2], smv[qt * 4 + 3]};
                *(f32x4*)&smS[qt * 16 + quad * 4] = v;
            }
        }
        // s2 = W2·sumMu by MFMA (w2n => negate at extract). Lean frag build.
        bf16x8 bs0, bs1;
        {
            f32x4 pA = *(const f32x4*)&smS[quad * 8];
            f32x4 pB = *(const f32x4*)&smS[quad * 8 + 4];
#pragma unroll
            for (int e = 0; e < 4; ++e) {
                bf16 h = (bf16)pA[e];
                bs0[e] = (l15 == 0) ? h : ((l15 == 1) ? (bf16)(pA[e] - (float)h) : (bf16)0.f);
                bf16 g = (bf16)pB[e];
                bs0[4 + e] = (l15 == 0) ? g : ((l15 == 1) ? (bf16)(pB[e] - (float)g) : (bf16)0.f);
            }
            pA = *(const f32x4*)&smS[32 + quad * 8];
            pB = *(const f32x4*)&smS[32 + quad * 8 + 4];
#pragma unroll
            for (int e = 0; e < 4; ++e) {
                bf16 h = (bf16)pA[e];
                bs1[e] = (l15 == 0) ? h : ((l15 == 1) ? (bf16)(pA[e] - (float)h) : (bf16)0.f);
                bf16 g = (bf16)pB[e];
                bs1[4 + e] = (l15 == 0) ? g : ((l15 == 1) ? (bf16)(pB[e] - (float)g) : (bf16)0.f);
            }
        }
        f32x4 s2q[4];
#pragma unroll
        for (int qt = 0; qt < 4; ++qt) {
            f32x4 a = MFMA16(w2n[qt][0], bs0, zero4);
            a = MFMA16(w2n[qt][1], bs1, a);
#pragma unroll
            for (int e = 0; e < 4; ++e)
                s2q[qt][e] = -(__shfl(a[e], quad * 16) + __shfl(a[e], quad * 16 + 1));
        }

        // main pass: per (kt,qt): base-MFMA -> two w2n MFMAs = base - acc
#pragma unroll
        for (int i = 0; i < 16; ++i) smv[i] = 0.f;
#pragma unroll
        for (int kt = 0; kt < 8; ++kt) {
            bf16x8 bB; BUILD_BB(bB, kt);
            const int row = (kt * 16 + l15) * 64;
            bf16x8 m0 = *(const bf16x8*)&muS[row + ((quad) ^ sw) * 8];
            bf16x8 m1 = *(const bf16x8*)&muS[row + ((4 + quad) ^ sw) * 8];
#pragma unroll
            for (int qt = 0; qt < 4; ++qt) {
                f32x4 a = MFMA16(aB[qt], bB, zero4);
                a = MFMA16(w2n[qt][0], m0, a);
                a = MFMA16(w2n[qt][1], m1, a);
                bf16x4 h;
#pragma unroll
                for (int e = 0; e < 4; ++e) {
                    float v = fmaxf(a[e] + s2q[qt][e], 0.f);
                    smv[qt * 4 + e] += v;
                    h[e] = (bf16)v;
                }
                *(bf16x4*)&muS[row + ((2 * qt + (quad >> 1)) ^ sw) * 8 + 4 * (quad & 1)] = h;
            }
        }
    }

    // ---------------- readout (wave-internal) ----------------
#pragma unroll
    for (int m = 1; m <= 8; m <<= 1)
#pragma unroll
        for (int i = 0; i < 16; ++i) smv[i] += __shfl_xor(smv[i], m);
    if (l15 == 0) {
#pragma unroll
        for (int qt = 0; qt < 4; ++qt) {
            f32x4 v = {smv[qt * 4], smv[qt * 4 + 1], smv[qt * 4 + 2], smv[qt * 4 + 3]};
            *(f32x4*)&smS[qt * 16 + quad * 4] = v;
        }
    }

    float pl = 0.f;
#pragma unroll
    for (int c = 0; c < 16; ++c) {
        f32x4 sv = *(const f32x4*)&smS[c * 4];
        f32x4 w6 = *(const f32x4*)&W6g[lane * 64 + c * 4];
#pragma unroll
        for (int e = 0; e < 4; ++e) pl = fmaf(sv[e], w6[e], pl);
    }
    float qa = fmaxf(pl, 0.f) * W5g[lane];
#pragma unroll
    for (int m = 1; m < 64; m <<= 1) qa += __shfl_xor(qa, m);

    f32x4 uf[2][2];
#pragma unroll
    for (int s = 0; s < 2; ++s) {
        uf[s][0] = *(const f32x4*)&uS[s * 32 + quad * 8];
        uf[s][1] = *(const f32x4*)&uS[s * 32 + quad * 8 + 4];
    }

    float res[8];
#pragma unroll
    for (int kt = 0; kt < 8; ++kt) {
        const int row = (kt * 16 + l15) * 64;
        bf16x8 m0 = *(const bf16x8*)&muS[row + ((quad) ^ sw) * 8];
        bf16x8 m1 = *(const bf16x8*)&muS[row + ((4 + quad) ^ sw) * 8];
        float r = 0.f;
#pragma unroll
        for (int j = 0; j < 4; ++j) {
            r = fmaf((float)m0[j],     uf[0][0][j], r);
            r = fmaf((float)m0[4 + j], uf[0][1][j], r);
            r = fmaf((float)m1[j],     uf[1][0][j], r);
            r = fmaf((float)m1[4 + j], uf[1][1][j], r);
        }
        r += __shfl_xor(r, 16); r += __shfl_xor(r, 32);
        res[kt] = r;
    }
    float rA0 = (quad & 1) ? res[1] : res[0];
    float rA1 = (quad & 1) ? res[3] : res[2];
    float rA  = (quad & 2) ? rA1 : rA0;
    float rB0 = (quad & 1) ? res[5] : res[4];
    float rB1 = (quad & 1) ? res[7] : res[6];
    float rB  = (quad & 2) ? rB1 : rB0;
    Outg[b * 128 + lane]      = qa + rA;   // k = lane       (kt = quad)
    Outg[b * 128 + 64 + lane] = qa + rB;   // k = lane + 64  (kt = quad + 4)
}

extern "C" void kernel_launch(void* const* d_in, const int* in_sizes, int n_in,
                              void* d_out, int out_size, void* d_ws, size_t ws_size,
                              hipStream_t stream) {
    (void)n_in; (void)d_ws; (void)ws_size; (void)out_size;
    const int B = in_sizes[0] >> 7;   // 4096
    qnet_kernel<<<B, 64, 0, stream>>>(
        (const float*)d_in[0], (const float*)d_in[1], (const float*)d_in[2],
        (const float*)d_in[3], (const float*)d_in[4], (const float*)d_in[5],
        (const float*)d_in[6], (const float*)d_in[7], (const float*)d_in[8],
        (float*)d_out);
}

// Round 19
// 126.461 us; speedup vs baseline: 1.1357x; 1.1357x over previous
//
#include <hip/hip_runtime.h>

typedef __bf16 bf16;
typedef __bf16 bf16x4 __attribute__((ext_vector_type(4)));
typedef __bf16 bf16x8 __attribute__((ext_vector_type(8)));
typedef float  f32x4  __attribute__((ext_vector_type(4)));

#define MFMA16(a, b, c) __builtin_amdgcn_mfma_f32_16x16x32_bf16((a), (b), (c), 0, 0, 0)

// R20 = R17 (65.2us best) with the s2 chain's LDS ROUND-TRIP REMOVED:
//  * After the l15 butterfly, EVERY lane holds the full sumMu (l15-uniform per
//    quad). The in-loop smS publish + pA/pB read-back (~150-250 serial cyc x3
//    iters, plus divergent l15==0 branch) is replaced by a direct register
//    build: bs element p = 32s + quad*8 + c*4 + e comes from
//    smv[(2s + (quad>>1))*4 + e] at lane ((2quad+c)&3)*16+l15 -- 32 bpermute
//    shfls + cndmask (register index takes only 2 values per s). Bit-identical
//    math -> absmax 524288.
//  * Also deletes the pA/pB transients (-16 arch regs at the pressure peak).
//  * R18 lesson: base-by-MFMA (3-deep dep chains) regressed 50% -- the VALU
//    epilogue co-issues with MFMA and is effectively free. Keep R17 epilogue.
// LAUNCH-BOUNDS RULE (R2/R4/R8): never min-waves>2.
__global__ __launch_bounds__(64, 2)
void qnet_kernel(const float* __restrict__ Xg, const float* __restrict__ Wg,
                 const float* __restrict__ W1g, const float* __restrict__ W2g,
                 const float* __restrict__ W3g, const float* __restrict__ W4g,
                 const float* __restrict__ W5g, const float* __restrict__ W6g,
                 const float* __restrict__ W7g, float* __restrict__ Outg)
{
    __shared__ __align__(16) bf16 muS[128 * 64];   // 16384 B, packed + swizzled
    __shared__ __align__(16) float uS[64];         // 256 B
    __shared__ __align__(16) float smS[64];        // 256 B  (readout only)

    const int lane = threadIdx.x;       // 0..63, one wave
    const int b    = blockIdx.x;
    const int l15  = lane & 15;
    const int quad = lane >> 4;
    const int sw   = l15 & 7;           // swizzle key: k&7 == l15&7 for k=16kt+l15

    // ---------------- per-batch vectors (6 persistent regs) ----------------
    float xv0 = Xg[b * 128 + lane], xv1 = Xg[b * 128 + 64 + lane];
    float wv0 = Wg[b * 128 + lane], wv1 = Wg[b * 128 + 64 + lane];

    float Ap = fmaxf(wv0, 0.f) + fmaxf(wv1, 0.f);
    float Bn = fmaxf(-wv0, 0.f) + fmaxf(-wv1, 0.f);
#pragma unroll
    for (int m = 1; m < 64; m <<= 1) { Ap += __shfl_xor(Ap, m); Bn += __shfl_xor(Bn, m); }

    // v3p/v3m at q=lane (exact fp32), distribute to (qt,e) epilogue layout
    float sp = 0.f, sm = 0.f;
#pragma unroll
    for (int c = 0; c < 16; ++c) {
        f32x4 w4 = *(const f32x4*)&W4g[c * 4];
        f32x4 w3 = *(const f32x4*)&W3g[lane * 64 + c * 4];
#pragma unroll
        for (int e = 0; e < 4; ++e) {
            sp += fmaxf(w4[e], 0.f) * w3[e];
            sm += fmaxf(-w4[e], 0.f) * w3[e];
        }
    }
    float w1C[16], v3pC[16], v3mC[16];
#pragma unroll
    for (int qt = 0; qt < 4; ++qt) {
        f32x4 w1v = *(const f32x4*)&W1g[qt * 16 + quad * 4];
#pragma unroll
        for (int e = 0; e < 4; ++e) {
            const int q = qt * 16 + quad * 4 + e;
            v3pC[qt * 4 + e] = __shfl(sp, q);
            v3mC[qt * 4 + e] = __shfl(sm, q);
            w1C[qt * 4 + e]  = w1v[e];
        }
    }

    // u[p=lane] = W5b @ W7[:,p] -> uS (wave-private LDS)
    {
        float u = 0.f;
#pragma unroll
        for (int c = 0; c < 16; ++c) {
            f32x4 w5v = *(const f32x4*)&W5g[64 + c * 4];
#pragma unroll
            for (int e = 0; e < 4; ++e) u += w5v[e] * W7g[(c * 4 + e) * 64 + lane];
        }
        uS[lane] = u;
    }

    // W2 A-fragments (bf16 hi only)
    bf16x8 w2h[4][2];
#pragma unroll
    for (int qt = 0; qt < 4; ++qt)
#pragma unroll
        for (int s = 0; s < 2; ++s) {
            const float* src = &W2g[(qt * 16 + l15) * 64 + s * 32 + quad * 8];
            f32x4 f0 = *(const f32x4*)src;
            f32x4 f1 = *(const f32x4*)(src + 4);
            bf16x8 h;
#pragma unroll
            for (int e = 0; e < 4; ++e) { h[e] = (bf16)f0[e]; h[4 + e] = (bf16)f1[e]; }
            w2h[qt][s] = h;
        }

    // ---------------- mu1 = relu(base), exact fp32; accumulate smv ----------------
    float smv[16];
#pragma unroll
    for (int i = 0; i < 16; ++i) smv[i] = 0.f;
#pragma unroll
    for (int kt = 0; kt < 8; ++kt) {
        const int src = (kt & 3) * 16 + l15;
        float xs_ = __shfl((kt < 4) ? xv0 : xv1, src);
        float ws_ = __shfl((kt < 4) ? wv0 : wv1, src);
        float ap_ = Ap - fmaxf(ws_, 0.f);
        float bn_ = Bn - fmaxf(-ws_, 0.f);
        const int row = (kt * 16 + l15) * 64;
#pragma unroll
        for (int qt = 0; qt < 4; ++qt) {
            bf16x4 h;
#pragma unroll
            for (int e = 0; e < 4; ++e) {
                float t = fmaf(xs_, w1C[qt * 4 + e],
                          fmaf(ap_, v3pC[qt * 4 + e], bn_ * v3mC[qt * 4 + e]));
                float v = fmaxf(t, 0.f);
                smv[qt * 4 + e] += v;
                h[e] = (bf16)v;
            }
            *(bf16x4*)&muS[row + ((2 * qt + (quad >> 1)) ^ sw) * 8 + 4 * (quad & 1)] = h;
        }
    }

    // ---------------- 3 iterations, zero barriers ----------------
    const f32x4 zero4 = {0.f, 0.f, 0.f, 0.f};
    for (int it = 0; it < 3; ++it) {
        // sumMu: l15 butterfly -> every lane holds full sumMu (quad-sliced)
#pragma unroll
        for (int m = 1; m <= 8; m <<= 1)
#pragma unroll
            for (int i = 0; i < 16; ++i) smv[i] += __shfl_xor(smv[i], m);

        // bs frags built DIRECTLY from smv registers (no LDS round-trip):
        // bs{s}[c*4+e] = sumMu[32s + quad*8 + c*4 + e] hi/lo split on l15.
        bf16x8 bs0, bs1;
        {
            const int srcA = ((2 * quad) & 3) * 16 + l15;       // c = 0
            const int srcB = ((2 * quad + 1) & 3) * 16 + l15;   // c = 1
#pragma unroll
            for (int e = 0; e < 4; ++e) {
                float a0 = __shfl(smv[e], srcA),      b0 = __shfl(smv[4 + e], srcA);
                float a1 = __shfl(smv[e], srcB),      b1 = __shfl(smv[4 + e], srcB);
                float f00 = (quad < 2) ? a0 : b0;     // bs0 elem e    (c=0)
                float f01 = (quad < 2) ? a1 : b1;     // bs0 elem 4+e  (c=1)
                float a2 = __shfl(smv[8 + e], srcA),  b2 = __shfl(smv[12 + e], srcA);
                float a3 = __shfl(smv[8 + e], srcB),  b3 = __shfl(smv[12 + e], srcB);
                float f10 = (quad < 2) ? a2 : b2;     // bs1 elem e
                float f11 = (quad < 2) ? a3 : b3;     // bs1 elem 4+e
                bf16 h;
                h = (bf16)f00; bs0[e]     = (l15 == 0) ? h : ((l15 == 1) ? (bf16)(f00 - (float)h) : (bf16)0.f);
                h = (bf16)f01; bs0[4 + e] = (l15 == 0) ? h : ((l15 == 1) ? (bf16)(f01 - (float)h) : (bf16)0.f);
                h = (bf16)f10; bs1[e]     = (l15 == 0) ? h : ((l15 == 1) ? (bf16)(f10 - (float)h) : (bf16)0.f);
                h = (bf16)f11; bs1[4 + e] = (l15 == 0) ? h : ((l15 == 1) ? (bf16)(f11 - (float)h) : (bf16)0.f);
            }
        }
        f32x4 s2q[4];
#pragma unroll
        for (int qt = 0; qt < 4; ++qt) {
            f32x4 a = MFMA16(w2h[qt][0], bs0, zero4);
            a = MFMA16(w2h[qt][1], bs1, a);
#pragma unroll
            for (int e = 0; e < 4; ++e)
                s2q[qt][e] = __shfl(a[e], quad * 16) + __shfl(a[e], quad * 16 + 1);
        }

        // main pass: 64 MFMAs + fused epilogue (base recomputed fp32-exact,
        // per-kt scalars recomputed via shfl -- no persistent arrays)
#pragma unroll
        for (int i = 0; i < 16; ++i) smv[i] = 0.f;
#pragma unroll
        for (int kt = 0; kt < 8; ++kt) {
            const int src = (kt & 3) * 16 + l15;
            float xs_ = __shfl((kt < 4) ? xv0 : xv1, src);
            float ws_ = __shfl((kt < 4) ? wv0 : wv1, src);
            float ap_ = Ap - fmaxf(ws_, 0.f);
            float bn_ = Bn - fmaxf(-ws_, 0.f);
            const int row = (kt * 16 + l15) * 64;
            bf16x8 m0 = *(const bf16x8*)&muS[row + ((quad) ^ sw) * 8];
            bf16x8 m1 = *(const bf16x8*)&muS[row + ((4 + quad) ^ sw) * 8];
#pragma unroll
            for (int qt = 0; qt < 4; ++qt) {
                f32x4 a = MFMA16(w2h[qt][0], m0, zero4);
                a = MFMA16(w2h[qt][1], m1, a);
                bf16x4 h;
#pragma unroll
                for (int e = 0; e < 4; ++e) {
                    float t = fmaf(xs_, w1C[qt * 4 + e], s2q[qt][e]);
                    t = fmaf(ap_, v3pC[qt * 4 + e], t);
                    t = fmaf(bn_, v3mC[qt * 4 + e], t);
                    float v = fmaxf(t - a[e], 0.f);
                    smv[qt * 4 + e] += v;
                    h[e] = (bf16)v;
                }
                *(bf16x4*)&muS[row + ((2 * qt + (quad >> 1)) ^ sw) * 8 + 4 * (quad & 1)] = h;
            }
        }
    }

    // ---------------- readout (wave-internal) ----------------
#pragma unroll
    for (int m = 1; m <= 8; m <<= 1)
#pragma unroll
        for (int i = 0; i < 16; ++i) smv[i] += __shfl_xor(smv[i], m);
    if (l15 == 0) {
#pragma unroll
        for (int qt = 0; qt < 4; ++qt) {
            f32x4 v = {smv[qt * 4], smv[qt * 4 + 1], smv[qt * 4 + 2], smv[qt * 4 + 3]};
            *(f32x4*)&smS[qt * 16 + quad * 4] = v;
        }
    }

    float pl = 0.f;
#pragma unroll
    for (int c = 0; c < 16; ++c) {
        f32x4 sv = *(const f32x4*)&smS[c * 4];
        f32x4 w6 = *(const f32x4*)&W6g[lane * 64 + c * 4];
#pragma unroll
        for (int e = 0; e < 4; ++e) pl = fmaf(sv[e], w6[e], pl);
    }
    float qa = fmaxf(pl, 0.f) * W5g[lane];
#pragma unroll
    for (int m = 1; m < 64; m <<= 1) qa += __shfl_xor(qa, m);

    f32x4 uf[2][2];
#pragma unroll
    for (int s = 0; s < 2; ++s) {
        uf[s][0] = *(const f32x4*)&uS[s * 32 + quad * 8];
        uf[s][1] = *(const f32x4*)&uS[s * 32 + quad * 8 + 4];
    }

    float res[8];
#pragma unroll
    for (int kt = 0; kt < 8; ++kt) {
        const int row = (kt * 16 + l15) * 64;
        bf16x8 m0 = *(const bf16x8*)&muS[row + ((quad) ^ sw) * 8];
        bf16x8 m1 = *(const bf16x8*)&muS[row + ((4 + quad) ^ sw) * 8];
        float r = 0.f;
#pragma unroll
        for (int j = 0; j < 4; ++j) {
            r = fmaf((float)m0[j],     uf[0][0][j], r);
            r = fmaf((float)m0[4 + j], uf[0][1][j], r);
            r = fmaf((float)m1[j],     uf[1][0][j], r);
            r = fmaf((float)m1[4 + j], uf[1][1][j], r);
        }
        r += __shfl_xor(r, 16); r += __shfl_xor(r, 32);
        res[kt] = r;
    }
    float rA0 = (quad & 1) ? res[1] : res[0];
    float rA1 = (quad & 1) ? res[3] : res[2];
    float rA  = (quad & 2) ? rA1 : rA0;
    float rB0 = (quad & 1) ? res[5] : res[4];
    float rB1 = (quad & 1) ? res[7] : res[6];
    float rB  = (quad & 2) ? rB1 : rB0;
    Outg[b * 128 + lane]      = qa + rA;   // k = lane       (kt = quad)
    Outg[b * 128 + 64 + lane] = qa + rB;   // k = lane + 64  (kt = quad + 4)
}

extern "C" void kernel_launch(void* const* d_in, const int* in_sizes, int n_in,
                              void* d_out, int out_size, void* d_ws, size_t ws_size,
                              hipStream_t stream) {
    (void)n_in; (void)d_ws; (void)ws_size; (void)out_size;
    const int B = in_sizes[0] >> 7;   // 4096
    qnet_kernel<<<B, 64, 0, stream>>>(
        (const float*)d_in[0], (const float*)d_in[1], (const float*)d_in[2],
        (const float*)d_in[3], (const float*)d_in[4], (const float*)d_in[5],
        (const float*)d_in[6], (const float*)d_in[7], (const float*)d_in[8],
        (float*)d_out);
}

// Round 20
// 125.459 us; speedup vs baseline: 1.1448x; 1.0080x over previous
//
#include <hip/hip_runtime.h>

typedef __bf16 bf16;
typedef __bf16 bf16x4 __attribute__((ext_vector_type(4)));
typedef __bf16 bf16x8 __attribute__((ext_vector_type(8)));
typedef float  f32x4  __attribute__((ext_vector_type(4)));

#define MFMA16(a, b, c) __builtin_amdgcn_mfma_f32_16x16x32_bf16((a), (b), (c), 0, 0, 0)

// R20 = EXACT REVERT TO R17 (measured frontier: 65.2us).
// Session ledger (19 rounds):
//  * Winning structure: wave-per-batch, zero barriers, mu bf16 128x64 packed+
//    XOR-swizzled in LDS (16.4KB -> 9 waves/CU, the hard occupancy cap),
//    s2 = W2·sumMu by 2 MFMAs (sumMu free from epilogue + l15 butterfly),
//    VALU epilogue with base recomputed fp32-exact from 6 regs via shfl.
//  * Verified negative results: launch_bounds min-waves>2 => catastrophic spill
//    (R2/R4/R8); in-loop fp32 global matvec => spill (R9/R12); >~30 extra arch
//    transients => spill (R13/R15); base-by-MFMA 3-dep chains => -50% (R18,
//    VALU epilogue co-issues with MFMA and is ~free); dual-batch ILP-for-TLP
//    => -40% (R14); shfl-for-LDS s2 build => neutral, shfl IS ds_bpermute on
//    the same DS pipe (R19); k-split 2-wave => -30% (R10).
//  * Kernel is DS+VALU latency-bound at 2 waves/SIMD, both pipes <50%,
//    occupancy LDS-capped. Residual ~1.3MB scratch read traffic costs ~1us
//    (R18 proved removing it while adding MFMA deps loses 35us).
__global__ __launch_bounds__(64, 2)
void qnet_kernel(const float* __restrict__ Xg, const float* __restrict__ Wg,
                 const float* __restrict__ W1g, const float* __restrict__ W2g,
                 const float* __restrict__ W3g, const float* __restrict__ W4g,
                 const float* __restrict__ W5g, const float* __restrict__ W6g,
                 const float* __restrict__ W7g, float* __restrict__ Outg)
{
    __shared__ __align__(16) bf16 muS[128 * 64];   // 16384 B, packed + swizzled
    __shared__ __align__(16) float uS[64];         // 256 B
    __shared__ __align__(16) float smS[64];        // 256 B  sumMu broadcast

    const int lane = threadIdx.x;       // 0..63, one wave
    const int b    = blockIdx.x;
    const int l15  = lane & 15;
    const int quad = lane >> 4;
    const int sw   = l15 & 7;           // swizzle key: k&7 == l15&7 for k=16kt+l15

    // ---------------- per-batch vectors (6 persistent regs) ----------------
    float xv0 = Xg[b * 128 + lane], xv1 = Xg[b * 128 + 64 + lane];
    float wv0 = Wg[b * 128 + lane], wv1 = Wg[b * 128 + 64 + lane];

    float Ap = fmaxf(wv0, 0.f) + fmaxf(wv1, 0.f);
    float Bn = fmaxf(-wv0, 0.f) + fmaxf(-wv1, 0.f);
#pragma unroll
    for (int m = 1; m < 64; m <<= 1) { Ap += __shfl_xor(Ap, m); Bn += __shfl_xor(Bn, m); }

    // v3p/v3m at q=lane (exact fp32), distribute to (qt,e) epilogue layout
    float sp = 0.f, sm = 0.f;
#pragma unroll
    for (int c = 0; c < 16; ++c) {
        f32x4 w4 = *(const f32x4*)&W4g[c * 4];
        f32x4 w3 = *(const f32x4*)&W3g[lane * 64 + c * 4];
#pragma unroll
        for (int e = 0; e < 4; ++e) {
            sp += fmaxf(w4[e], 0.f) * w3[e];
            sm += fmaxf(-w4[e], 0.f) * w3[e];
        }
    }
    float w1C[16], v3pC[16], v3mC[16];
#pragma unroll
    for (int qt = 0; qt < 4; ++qt) {
        f32x4 w1v = *(const f32x4*)&W1g[qt * 16 + quad * 4];
#pragma unroll
        for (int e = 0; e < 4; ++e) {
            const int q = qt * 16 + quad * 4 + e;
            v3pC[qt * 4 + e] = __shfl(sp, q);
            v3mC[qt * 4 + e] = __shfl(sm, q);
            w1C[qt * 4 + e]  = w1v[e];
        }
    }

    // u[p=lane] = W5b @ W7[:,p] -> uS (wave-private LDS)
    {
        float u = 0.f;
#pragma unroll
        for (int c = 0; c < 16; ++c) {
            f32x4 w5v = *(const f32x4*)&W5g[64 + c * 4];
#pragma unroll
            for (int e = 0; e < 4; ++e) u += w5v[e] * W7g[(c * 4 + e) * 64 + lane];
        }
        uS[lane] = u;
    }

    // W2 A-fragments (bf16 hi only)
    bf16x8 w2h[4][2];
#pragma unroll
    for (int qt = 0; qt < 4; ++qt)
#pragma unroll
        for (int s = 0; s < 2; ++s) {
            const float* src = &W2g[(qt * 16 + l15) * 64 + s * 32 + quad * 8];
            f32x4 f0 = *(const f32x4*)src;
            f32x4 f1 = *(const f32x4*)(src + 4);
            bf16x8 h;
#pragma unroll
            for (int e = 0; e < 4; ++e) { h[e] = (bf16)f0[e]; h[4 + e] = (bf16)f1[e]; }
            w2h[qt][s] = h;
        }

    // ---------------- mu1 = relu(base), exact fp32; accumulate smv ----------------
    float smv[16];
#pragma unroll
    for (int i = 0; i < 16; ++i) smv[i] = 0.f;
#pragma unroll
    for (int kt = 0; kt < 8; ++kt) {
        const int src = (kt & 3) * 16 + l15;
        float xs_ = __shfl((kt < 4) ? xv0 : xv1, src);
        float ws_ = __shfl((kt < 4) ? wv0 : wv1, src);
        float ap_ = Ap - fmaxf(ws_, 0.f);
        float bn_ = Bn - fmaxf(-ws_, 0.f);
        const int row = (kt * 16 + l15) * 64;
#pragma unroll
        for (int qt = 0; qt < 4; ++qt) {
            bf16x4 h;
#pragma unroll
            for (int e = 0; e < 4; ++e) {
                float t = fmaf(xs_, w1C[qt * 4 + e],
                          fmaf(ap_, v3pC[qt * 4 + e], bn_ * v3mC[qt * 4 + e]));
                float v = fmaxf(t, 0.f);
                smv[qt * 4 + e] += v;
                h[e] = (bf16)v;
            }
            *(bf16x4*)&muS[row + ((2 * qt + (quad >> 1)) ^ sw) * 8 + 4 * (quad & 1)] = h;
        }
    }

    // ---------------- 3 iterations, zero barriers ----------------
    const f32x4 zero4 = {0.f, 0.f, 0.f, 0.f};
    for (int it = 0; it < 3; ++it) {
        // sumMu: l15 butterfly + publish to smS
#pragma unroll
        for (int m = 1; m <= 8; m <<= 1)
#pragma unroll
            for (int i = 0; i < 16; ++i) smv[i] += __shfl_xor(smv[i], m);
        if (l15 == 0) {
#pragma unroll
            for (int qt = 0; qt < 4; ++qt) {
                f32x4 v = {smv[qt * 4], smv[qt * 4 + 1], smv[qt * 4 + 2], smv[qt * 4 + 3]};
                *(f32x4*)&smS[qt * 16 + quad * 4] = v;
            }
        }
        // s2 = W2·sumMu by MFMA: lean frag build (Sh col 0, Sl col 1)
        bf16x8 bs0, bs1;
        {
            f32x4 pA = *(const f32x4*)&smS[quad * 8];
            f32x4 pB = *(const f32x4*)&smS[quad * 8 + 4];
#pragma unroll
            for (int e = 0; e < 4; ++e) {
                bf16 h = (bf16)pA[e];
                bs0[e] = (l15 == 0) ? h : ((l15 == 1) ? (bf16)(pA[e] - (float)h) : (bf16)0.f);
                bf16 g = (bf16)pB[e];
                bs0[4 + e] = (l15 == 0) ? g : ((l15 == 1) ? (bf16)(pB[e] - (float)g) : (bf16)0.f);
            }
            pA = *(const f32x4*)&smS[32 + quad * 8];
            pB = *(const f32x4*)&smS[32 + quad * 8 + 4];
#pragma unroll
            for (int e = 0; e < 4; ++e) {
                bf16 h = (bf16)pA[e];
                bs1[e] = (l15 == 0) ? h : ((l15 == 1) ? (bf16)(pA[e] - (float)h) : (bf16)0.f);
                bf16 g = (bf16)pB[e];
                bs1[4 + e] = (l15 == 0) ? g : ((l15 == 1) ? (bf16)(pB[e] - (float)g) : (bf16)0.f);
            }
        }
        f32x4 s2q[4];
#pragma unroll
        for (int qt = 0; qt < 4; ++qt) {
            f32x4 a = MFMA16(w2h[qt][0], bs0, zero4);
            a = MFMA16(w2h[qt][1], bs1, a);
#pragma unroll
            for (int e = 0; e < 4; ++e)
                s2q[qt][e] = __shfl(a[e], quad * 16) + __shfl(a[e], quad * 16 + 1);
        }

        // main pass: 64 MFMAs + fused epilogue (base recomputed fp32-exact,
        // per-kt scalars recomputed via shfl -- no persistent arrays)
#pragma unroll
        for (int i = 0; i < 16; ++i) smv[i] = 0.f;
#pragma unroll
        for (int kt = 0; kt < 8; ++kt) {
            const int src = (kt & 3) * 16 + l15;
            float xs_ = __shfl((kt < 4) ? xv0 : xv1, src);
            float ws_ = __shfl((kt < 4) ? wv0 : wv1, src);
            float ap_ = Ap - fmaxf(ws_, 0.f);
            float bn_ = Bn - fmaxf(-ws_, 0.f);
            const int row = (kt * 16 + l15) * 64;
            bf16x8 m0 = *(const bf16x8*)&muS[row + ((quad) ^ sw) * 8];
            bf16x8 m1 = *(const bf16x8*)&muS[row + ((4 + quad) ^ sw) * 8];
#pragma unroll
            for (int qt = 0; qt < 4; ++qt) {
                f32x4 a = MFMA16(w2h[qt][0], m0, zero4);
                a = MFMA16(w2h[qt][1], m1, a);
                bf16x4 h;
#pragma unroll
                for (int e = 0; e < 4; ++e) {
                    float t = fmaf(xs_, w1C[qt * 4 + e], s2q[qt][e]);
                    t = fmaf(ap_, v3pC[qt * 4 + e], t);
                    t = fmaf(bn_, v3mC[qt * 4 + e], t);
                    float v = fmaxf(t - a[e], 0.f);
                    smv[qt * 4 + e] += v;
                    h[e] = (bf16)v;
                }
                *(bf16x4*)&muS[row + ((2 * qt + (quad >> 1)) ^ sw) * 8 + 4 * (quad & 1)] = h;
            }
        }
    }

    // ---------------- readout (wave-internal) ----------------
#pragma unroll
    for (int m = 1; m <= 8; m <<= 1)
#pragma unroll
        for (int i = 0; i < 16; ++i) smv[i] += __shfl_xor(smv[i], m);
    if (l15 == 0) {
#pragma unroll
        for (int qt = 0; qt < 4; ++qt) {
            f32x4 v = {smv[qt * 4], smv[qt * 4 + 1], smv[qt * 4 + 2], smv[qt * 4 + 3]};
            *(f32x4*)&smS[qt * 16 + quad * 4] = v;
        }
    }

    float pl = 0.f;
#pragma unroll
    for (int c = 0; c < 16; ++c) {
        f32x4 sv = *(const f32x4*)&smS[c * 4];
        f32x4 w6 = *(const f32x4*)&W6g[lane * 64 + c * 4];
#pragma unroll
        for (int e = 0; e < 4; ++e) pl = fmaf(sv[e], w6[e], pl);
    }
    float qa = fmaxf(pl, 0.f) * W5g[lane];
#pragma unroll
    for (int m = 1; m < 64; m <<= 1) qa += __shfl_xor(qa, m);

    f32x4 uf[2][2];
#pragma unroll
    for (int s = 0; s < 2; ++s) {
        uf[s][0] = *(const f32x4*)&uS[s * 32 + quad * 8];
        uf[s][1] = *(const f32x4*)&uS[s * 32 + quad * 8 + 4];
    }

    float res[8];
#pragma unroll
    for (int kt = 0; kt < 8; ++kt) {
        const int row = (kt * 16 + l15) * 64;
        bf16x8 m0 = *(const bf16x8*)&muS[row + ((quad) ^ sw) * 8];
        bf16x8 m1 = *(const bf16x8*)&muS[row + ((4 + quad) ^ sw) * 8];
        float r = 0.f;
#pragma unroll
        for (int j = 0; j < 4; ++j) {
            r = fmaf((float)m0[j],     uf[0][0][j], r);
            r = fmaf((float)m0[4 + j], uf[0][1][j], r);
            r = fmaf((float)m1[j],     uf[1][0][j], r);
            r = fmaf((float)m1[4 + j], uf[1][1][j], r);
        }
        r += __shfl_xor(r, 16); r += __shfl_xor(r, 32);
        res[kt] = r;
    }
    float rA0 = (quad & 1) ? res[1] : res[0];
    float rA1 = (quad & 1) ? res[3] : res[2];
    float rA  = (quad & 2) ? rA1 : rA0;
    float rB0 = (quad & 1) ? res[5] : res[4];
    float rB1 = (quad & 1) ? res[7] : res[6];
    float rB  = (quad & 2) ? rB1 : rB0;
    Outg[b * 128 + lane]      = qa + rA;   // k = lane       (kt = quad)
    Outg[b * 128 + 64 + lane] = qa + rB;   // k = lane + 64  (kt = quad + 4)
}

extern "C" void kernel_launch(void* const* d_in, const int* in_sizes, int n_in,
                              void* d_out, int out_size, void* d_ws, size_t ws_size,
                              hipStream_t stream) {
    (void)n_in; (void)d_ws; (void)ws_size; (void)out_size;
    const int B = in_sizes[0] >> 7;   // 4096
    qnet_kernel<<<B, 64, 0, stream>>>(
        (const float*)d_in[0], (const float*)d_in[1], (const float*)d_in[2],
        (const float*)d_in[3], (const float*)d_in[4], (const float*)d_in[5],
        (const float*)d_in[6], (const float*)d_in[7], (const float*)d_in[8],
        (float*)d_out);
}